// Round 1
// baseline (23642.564 us; speedup 1.0000x reference)
//
#include <hip/hip_runtime.h>
#include <cstddef>

// Problem constants
#define BB 4
#define TT 512
#define EE 1024
#define G4 4096      // 4*EE
#define VV 32000
#define EOSI 31999
#define LOG_BOUND (-1.0005003335835335e-3f)  // log(0.999)
#define NBLK 256     // persistent-kernel grid; 1 block/CU (LDS-bound), all co-resident

__device__ __forceinline__ float softplusf(float x) {
  return fmaxf(x, 0.0f) + log1pf(expf(-fabsf(x)));
}
__device__ __forceinline__ float sigmoidf(float x) {
  return 1.0f / (1.0f + expf(-x));
}

// Zero initial h state (slot 0 of each layer's h sequence) and the two
// grid-barrier regions (ws is poisoned 0xAA before every call).
__global__ void init_state(float* h0, float* h1, unsigned* bar0, unsigned* bar1) {
  int i = blockIdx.x * 256 + threadIdx.x;   // grid covers 4096
  h0[i] = 0.f; h1[i] = 0.f;
  if (i < 384) { bar0[i] = 0u; bar1[i] = 0u; }
}

// C[M,N] = Arows[M,K] @ Bw[N,K]^T + bias1[n] + bias2[n]
// mode 0: A row = m (A base pre-offset by caller)
// mode 1: A row = tokens[b*512 + t] with m = t*4+b   (embedding gather)
// mode 2: A row = t*4 + b + 4 with m = b*512+t       (h1 buffer -> logits layout)
// Tile 128x128, BK=16, 8x8 per thread, f32.
__global__ __launch_bounds__(256) void gemm_nt(
    const float* __restrict__ A, const float* __restrict__ Bw,
    float* __restrict__ C, int M, int N, int K,
    const float* __restrict__ bias1, const float* __restrict__ bias2,
    const int* __restrict__ tokens, int mode)
{
  __shared__ float As[16][132];   // [k][row], pad 132 to break bank conflicts
  __shared__ float Bs[16][132];
  const int tid  = threadIdx.x;
  const int bcol = blockIdx.x * 128;
  const int brow = blockIdx.y * 128;

  const int idx0 = tid, idx1 = tid + 256;
  const int ar0 = idx0 >> 2, ak0 = (idx0 & 3) * 4;
  const int ar1 = idx1 >> 2, ak1 = (idx1 & 3) * 4;

  long arow0, arow1;
  {
    int m0 = brow + ar0, m1 = brow + ar1;
    if (mode == 1) {
      arow0 = tokens[((m0 & 3) << 9) + (m0 >> 2)];
      arow1 = tokens[((m1 & 3) << 9) + (m1 >> 2)];
    } else if (mode == 2) {
      arow0 = ((m0 & 511) << 2) + (m0 >> 9) + 4;
      arow1 = ((m1 & 511) << 2) + (m1 >> 9) + 4;
    } else {
      arow0 = m0; arow1 = m1;
    }
  }
  const long brw0 = bcol + ar0, brw1 = bcol + ar1;

  float acc[8][8];
  #pragma unroll
  for (int i = 0; i < 8; ++i)
    #pragma unroll
    for (int j = 0; j < 8; ++j) acc[i][j] = 0.f;

  const int ti = tid >> 4, tj = tid & 15;

  for (int k0 = 0; k0 < K; k0 += 16) {
    float4 a0 = *(const float4*)(A  + arow0 * (long)K + k0 + ak0);
    float4 a1 = *(const float4*)(A  + arow1 * (long)K + k0 + ak1);
    float4 b0 = *(const float4*)(Bw + brw0  * (long)K + k0 + ak0);
    float4 b1 = *(const float4*)(Bw + brw1  * (long)K + k0 + ak1);
    __syncthreads();
    As[ak0+0][ar0] = a0.x; As[ak0+1][ar0] = a0.y; As[ak0+2][ar0] = a0.z; As[ak0+3][ar0] = a0.w;
    As[ak1+0][ar1] = a1.x; As[ak1+1][ar1] = a1.y; As[ak1+2][ar1] = a1.z; As[ak1+3][ar1] = a1.w;
    Bs[ak0+0][ar0] = b0.x; Bs[ak0+1][ar0] = b0.y; Bs[ak0+2][ar0] = b0.z; Bs[ak0+3][ar0] = b0.w;
    Bs[ak1+0][ar1] = b1.x; Bs[ak1+1][ar1] = b1.y; Bs[ak1+2][ar1] = b1.z; Bs[ak1+3][ar1] = b1.w;
    __syncthreads();
    #pragma unroll
    for (int kk = 0; kk < 16; ++kk) {
      float af[8], bf[8];
      #pragma unroll
      for (int i = 0; i < 8; ++i) af[i] = As[kk][ti*8 + i];
      #pragma unroll
      for (int j = 0; j < 8; ++j) bf[j] = Bs[kk][tj*8 + j];
      #pragma unroll
      for (int i = 0; i < 8; ++i)
        #pragma unroll
        for (int j = 0; j < 8; ++j) acc[i][j] += af[i] * bf[j];
    }
  }

  float bv[8];
  #pragma unroll
  for (int jj = 0; jj < 8; ++jj) {
    int n = bcol + tj*8 + jj;
    float bb = 0.f;
    if (bias1) bb += bias1[n];
    if (bias2) bb += bias2[n];
    bv[jj] = bb;
  }
  #pragma unroll
  for (int i = 0; i < 8; ++i) {
    int m = brow + ti*8 + i;
    float* cp = C + (size_t)m * N + bcol + tj*8;
    float4 v0 = make_float4(acc[i][0]+bv[0], acc[i][1]+bv[1], acc[i][2]+bv[2], acc[i][3]+bv[3]);
    float4 v1 = make_float4(acc[i][4]+bv[4], acc[i][5]+bv[5], acc[i][6]+bv[6], acc[i][7]+bv[7]);
    *(float4*)cp = v0;
    *(float4*)(cp + 4) = v1;
  }
}

// ---------------------------------------------------------------------------
// Persistent LSTM layer: one launch runs all 512 timesteps.
// 256 blocks x 256 threads; block owns h-dims [4*bid, 4*bid+4) -> 16 Whh rows
// (4 gates x 4 dims) staged in LDS ONCE (64 KB). c-state lives in LDS for the
// whole sequence. One grid barrier per step (two-level: 8 sub-counters of 32,
// then master, then a generation word everyone polls).
//
// Co-residency: LDS ~80.6 KB -> 1 block/CU; grid 256 <= 256 CUs, so all
// blocks are resident regardless of placement; the barrier cannot deadlock.
// ---------------------------------------------------------------------------
__global__ __launch_bounds__(256, 1) void lstm_persist(
    const float* __restrict__ gpre,   // [t][b][gate*1024 + j], t-stride 16384
    const float* __restrict__ Whh,    // (4096, 1024)
    float* __restrict__ hseq,         // 513 slots of (4,1024); slot 0 pre-zeroed
    unsigned* __restrict__ bar)       // barrier region (>= 320 uints, zeroed)
{
  __shared__ float wlds[16 * 1024];   // [r][k], r = gate*4 + jl      (64 KB)
  __shared__ float hlds[4 * 1024];    // [b][k]                       (16 KB)
  __shared__ float gsum[16][4];       // [r][b] reduced dot products
  __shared__ float gp[4][4][4];       // [gate][jl][b] gpre slice
  __shared__ float cst[4][4];         // [jl][b] persistent cell state

  const int tid = threadIdx.x;
  const int bid = blockIdx.x;

  // --- one-time: stage this block's 16 Whh rows into LDS (coalesced) ---
  {
    float4* wl4 = (float4*)wlds;
    const float4* w4 = (const float4*)Whh;
    for (int i = tid; i < 16 * 256; i += 256) {
      int r = i >> 8, k4 = i & 255;                    // local row, float4 col
      int grow = (r >> 2) * 1024 + bid * 4 + (r & 3);  // gate*1024 + j
      wl4[i] = w4[(size_t)grow * 256 + k4];
    }
  }
  if (tid < 16) cst[tid >> 2][tid & 3] = 0.f;

  const int rl = tid >> 4, ks = tid & 15;    // row 0..15, k-split 0..15
  const float4* wr4 = (const float4*)wlds + rl * 256;
  const float4* hl4 = (const float4*)hlds;

  unsigned tgt = 0;

  for (int t = 0; t < TT; ++t) {
    // stage h_t (16 KB) into LDS: 4 float4 per thread, fully coalesced
    {
      const float4* hsrc = (const float4*)(hseq + (size_t)t * G4);
      float4* hd = (float4*)hlds;
      #pragma unroll
      for (int i = 0; i < 4; ++i) hd[tid + 256 * i] = hsrc[tid + 256 * i];
    }
    // load gpre slice for this block: 16 float4 -> gp[gate][jl][b]
    if (tid < 16) {
      int b = tid >> 2, g = tid & 3;
      float4 v = *(const float4*)(gpre + (size_t)t * 16384 + b * 4096 + g * 1024 + bid * 4);
      gp[g][0][b] = v.x; gp[g][1][b] = v.y; gp[g][2][b] = v.z; gp[g][3][b] = v.w;
    }
    __syncthreads();

    // dot: row rl over k-chunk ks (64 floats), 4 batches.
    // h reads broadcast across the 4 rl-lanes sharing ks; w reads sit at the
    // b128 data floor (64 distinct 16B chunks per wave).
    float a0 = 0.f, a1 = 0.f, a2 = 0.f, a3 = 0.f;
    #pragma unroll
    for (int i = 0; i < 16; ++i) {
      int k4 = i * 16 + ks;
      float4 w  = wr4[k4];
      float4 h0 = hl4[k4];
      float4 h1 = hl4[256 + k4];
      float4 h2 = hl4[512 + k4];
      float4 h3 = hl4[768 + k4];
      a0 += w.x*h0.x + w.y*h0.y + w.z*h0.z + w.w*h0.w;
      a1 += w.x*h1.x + w.y*h1.y + w.z*h1.z + w.w*h1.w;
      a2 += w.x*h2.x + w.y*h2.y + w.z*h2.z + w.w*h2.w;
      a3 += w.x*h3.x + w.y*h3.y + w.z*h3.z + w.w*h3.w;
    }
    // reduce across the 16 ks-lanes (stays inside 16-lane groups of the wave)
    #pragma unroll
    for (int m = 1; m < 16; m <<= 1) {
      a0 += __shfl_xor(a0, m, 64);
      a1 += __shfl_xor(a1, m, 64);
      a2 += __shfl_xor(a2, m, 64);
      a3 += __shfl_xor(a3, m, 64);
    }
    if (ks < 4) {
      float v = (ks == 0) ? a0 : (ks == 1) ? a1 : (ks == 2) ? a2 : a3;
      gsum[rl][ks] = v;   // [r][b]
    }
    __syncthreads();

    // gates + state update + h write (16 threads: (jl, b))
    if (tid < 16) {
      int jl = tid >> 2, b = tid & 3;
      float gi = gp[0][jl][b] + gsum[ 0 + jl][b];
      float gf = gp[1][jl][b] + gsum[ 4 + jl][b];
      float gg = gp[2][jl][b] + gsum[ 8 + jl][b];
      float go = gp[3][jl][b] + gsum[12 + jl][b];
      float c = sigmoidf(gf) * cst[jl][b] + sigmoidf(gi) * tanhf(gg);
      cst[jl][b] = c;
      hseq[(size_t)(t + 1) * G4 + b * 1024 + bid * 4 + jl] = sigmoidf(go) * tanhf(c);
    }

    // ---- grid barrier (generation tgt+1) ----
    ++tgt;
    __syncthreads();
    if (tid == 0) {
      unsigned* subc = bar + (bid & 7) * 32;   // 128 B apart -> distinct lines
      unsigned* mast = bar + 8 * 32;
      unsigned* gen  = bar + 9 * 32;
      unsigned r = __hip_atomic_fetch_add(subc, 1u, __ATOMIC_ACQ_REL, __HIP_MEMORY_SCOPE_AGENT);
      if (r == 31) {
        unsigned mm = __hip_atomic_fetch_add(mast, 1u, __ATOMIC_ACQ_REL, __HIP_MEMORY_SCOPE_AGENT);
        if (mm == 7) {
          #pragma unroll
          for (int s = 0; s < 8; ++s)
            __hip_atomic_store(bar + s * 32, 0u, __ATOMIC_RELAXED, __HIP_MEMORY_SCOPE_AGENT);
          __hip_atomic_store(mast, 0u, __ATOMIC_RELAXED, __HIP_MEMORY_SCOPE_AGENT);
          __hip_atomic_store(gen, tgt, __ATOMIC_RELEASE, __HIP_MEMORY_SCOPE_AGENT);
        } else {
          while (__hip_atomic_load(gen, __ATOMIC_ACQUIRE, __HIP_MEMORY_SCOPE_AGENT) < tgt)
            __builtin_amdgcn_s_sleep(2);
        }
      } else {
        while (__hip_atomic_load(gen, __ATOMIC_ACQUIRE, __HIP_MEMORY_SCOPE_AGENT) < tgt)
          __builtin_amdgcn_s_sleep(2);
      }
    }
    __syncthreads();
  }
}

// Per-row (b,t) stats over logits in d_out:
__global__ __launch_bounds__(256) void row_stats(
    const float* __restrict__ logits, float* __restrict__ rowA, float* __restrict__ rowE)
{
  const int m = blockIdx.x;
  const float* row = logits + (size_t)m * VV;
  __shared__ float red[8];
  const int tid = threadIdx.x;

  float mx = -3.0e38f;
  for (int v = tid; v < EOSI; v += 256) mx = fmaxf(mx, row[v]);
  for (int off = 32; off; off >>= 1) mx = fmaxf(mx, __shfl_down(mx, off, 64));
  if ((tid & 63) == 0) red[tid >> 6] = mx;
  __syncthreads();
  if (tid == 0) red[4] = fmaxf(fmaxf(red[0], red[1]), fmaxf(red[2], red[3]));
  __syncthreads();
  mx = red[4];

  float s = 0.f;
  for (int v = tid; v < EOSI; v += 256) s += expf(row[v] - mx);
  for (int off = 32; off; off >>= 1) s += __shfl_down(s, off, 64);
  if ((tid & 63) == 0) red[tid >> 6] = s;
  __syncthreads();

  if (tid == 0) {
    s = red[0] + red[1] + red[2] + red[3];
    float lse_v = mx + logf(s);
    float eos = row[EOSI];
    int t = m & 511;                         // m = b*512 + t
    float log_lb = (float)(t + 1) * LOG_BOUND;
    float log_eos_lb = -softplusf(eos);      // log_sigmoid(-eos)
    float log_eos_ub = -softplusf(-eos);     // log_sigmoid(eos)
    float shift = log_lb + log_eos_lb;
    float f_lb = -expm1f(log_lb);            // 1 - exp(log_lb)
    float log_lb_eos = logf(f_lb) + log_eos_lb;
    float lprob_eos = log_lb_eos + softplusf(log_eos_ub - log_lb_eos);
    float aa = shift, bb = lprob_eos;
    float lse2 = fmaxf(aa, bb) + log1pf(expf(-fabsf(aa - bb)));
    rowA[m] = lse_v + lse2 - shift;
    rowE[m] = lprob_eos - lse2;
  }
}

// out[m][v] = logit - rowA[m] for v < EOSI ; rowE[m] at v == EOSI. In-place, float4.
__global__ __launch_bounds__(256) void finalize(
    float* __restrict__ out, const float* __restrict__ rowA, const float* __restrict__ rowE)
{
  const int m = blockIdx.y;
  const int v4 = blockIdx.x * 256 + threadIdx.x;   // 8000 float4 per row
  if (v4 >= 8000) return;
  float4* rp = (float4*)(out + (size_t)m * VV);
  const float A = rowA[m];
  float4 p = rp[v4];
  p.x -= A; p.y -= A; p.z -= A; p.w -= A;
  if (v4 == 7999) p.w = rowE[m];
  rp[v4] = p;
}

extern "C" void kernel_launch(void* const* d_in, const int* in_sizes, int n_in,
                              void* d_out, int out_size, void* d_ws, size_t ws_size,
                              hipStream_t stream)
{
  const int*   tokens = (const int*)  d_in[0];
  const float* emb    = (const float*)d_in[1];
  const float* Wproj  = (const float*)d_in[2];
  const float* Wih0   = (const float*)d_in[3];
  const float* Whh0   = (const float*)d_in[4];
  const float* bih0   = (const float*)d_in[5];
  const float* bhh0   = (const float*)d_in[6];
  const float* Wih1   = (const float*)d_in[7];
  const float* Whh1   = (const float*)d_in[8];
  const float* bih1   = (const float*)d_in[9];
  const float* bhh1   = (const float*)d_in[10];
  float* out = (float*)d_out;

  // workspace layout (floats): ~84 MB total
  float* ws = (float*)d_ws;
  float* g0   = ws;                        // 2048 x 4096
  float* g1   = g0 + (size_t)2048*4096;
  float* h0   = g1 + (size_t)2048*4096;    // 513 slots of (4,1024); slot 0 = zeros
  float* h1   = h0 + (size_t)513*4096;
  unsigned* bar0 = (unsigned*)(h1 + (size_t)513*4096);  // 384 uints each
  unsigned* bar1 = bar0 + 384;
  float* rowA = (float*)(bar1 + 384);      // 2048
  float* rowE = rowA + 2048;

  init_state<<<16, 256, 0, stream>>>(h0, h1, bar0, bar1);

  // layer 0 input gates for all (t,b): emb[tokens] @ Wih0^T + bih0 + bhh0
  gemm_nt<<<dim3(32, 16), 256, 0, stream>>>(emb, Wih0, g0, 2048, 4096, 1024,
                                            bih0, bhh0, tokens, 1);
  lstm_persist<<<NBLK, 256, 0, stream>>>(g0, Whh0, h0, bar0);

  // layer 1 input gates: h0_all @ Wih1^T + bih1 + bhh1
  gemm_nt<<<dim3(32, 16), 256, 0, stream>>>(h0 + 4096, Wih1, g1, 2048, 4096, 1024,
                                            bih1, bhh1, nullptr, 0);
  lstm_persist<<<NBLK, 256, 0, stream>>>(g1, Whh1, h1, bar1);

  // projection: logits into d_out, layout (b, t, v)
  gemm_nt<<<dim3(250, 16), 256, 0, stream>>>(h1, Wproj, out, 2048, 32000, 1024,
                                             nullptr, nullptr, nullptr, 2);

  row_stats<<<2048, 256, 0, stream>>>(out, rowA, rowE);
  finalize<<<dim3(32, 2048), 256, 0, stream>>>(out, rowA, rowE);
}

// Round 2
// 10179.120 us; speedup vs baseline: 2.3227x; 2.3227x over previous
//
#include <hip/hip_runtime.h>
#include <cstddef>

// Problem constants
#define BB 4
#define TT 512
#define EE 1024
#define G4 4096      // 4*EE
#define VV 32000
#define EOSI 31999
#define LOG_BOUND (-1.0005003335835335e-3f)  // log(0.999)
#define NBLK 256     // persistent grid: 256 blocks x 256 threads, all co-resident

__device__ __forceinline__ float softplusf(float x) {
  return fmaxf(x, 0.0f) + log1pf(expf(-fabsf(x)));
}
__device__ __forceinline__ float sigmoidf(float x) {
  return 1.0f / (1.0f + expf(-x));
}

// Zero the two flag arrays (ws is poisoned 0xAA before every call).
// h slot 0 is no longer read (h_0 is zeroed in LDS inside lstm_persist).
__global__ void init_state(unsigned* flag0, unsigned* flag1) {
  int i = threadIdx.x;   // one block of 256
  flag0[i] = 0u;
  flag1[i] = 0u;
}

// C[M,N] = Arows[M,K] @ Bw[N,K]^T + bias1[n] + bias2[n]
// mode 0: A row = m (A base pre-offset by caller)
// mode 1: A row = tokens[b*512 + t] with m = t*4+b   (embedding gather)
// mode 2: A row = t*4 + b + 4 with m = b*512+t       (h1 buffer -> logits layout)
// Tile 128x128, BK=16, 8x8 per thread, f32.
__global__ __launch_bounds__(256) void gemm_nt(
    const float* __restrict__ A, const float* __restrict__ Bw,
    float* __restrict__ C, int M, int N, int K,
    const float* __restrict__ bias1, const float* __restrict__ bias2,
    const int* __restrict__ tokens, int mode)
{
  __shared__ float As[16][132];   // [k][row], pad 132 to break bank conflicts
  __shared__ float Bs[16][132];
  const int tid  = threadIdx.x;
  const int bcol = blockIdx.x * 128;
  const int brow = blockIdx.y * 128;

  const int idx0 = tid, idx1 = tid + 256;
  const int ar0 = idx0 >> 2, ak0 = (idx0 & 3) * 4;
  const int ar1 = idx1 >> 2, ak1 = (idx1 & 3) * 4;

  long arow0, arow1;
  {
    int m0 = brow + ar0, m1 = brow + ar1;
    if (mode == 1) {
      arow0 = tokens[((m0 & 3) << 9) + (m0 >> 2)];
      arow1 = tokens[((m1 & 3) << 9) + (m1 >> 2)];
    } else if (mode == 2) {
      arow0 = ((m0 & 511) << 2) + (m0 >> 9) + 4;
      arow1 = ((m1 & 511) << 2) + (m1 >> 9) + 4;
    } else {
      arow0 = m0; arow1 = m1;
    }
  }
  const long brw0 = bcol + ar0, brw1 = bcol + ar1;

  float acc[8][8];
  #pragma unroll
  for (int i = 0; i < 8; ++i)
    #pragma unroll
    for (int j = 0; j < 8; ++j) acc[i][j] = 0.f;

  const int ti = tid >> 4, tj = tid & 15;

  for (int k0 = 0; k0 < K; k0 += 16) {
    float4 a0 = *(const float4*)(A  + arow0 * (long)K + k0 + ak0);
    float4 a1 = *(const float4*)(A  + arow1 * (long)K + k0 + ak1);
    float4 b0 = *(const float4*)(Bw + brw0  * (long)K + k0 + ak0);
    float4 b1 = *(const float4*)(Bw + brw1  * (long)K + k0 + ak1);
    __syncthreads();
    As[ak0+0][ar0] = a0.x; As[ak0+1][ar0] = a0.y; As[ak0+2][ar0] = a0.z; As[ak0+3][ar0] = a0.w;
    As[ak1+0][ar1] = a1.x; As[ak1+1][ar1] = a1.y; As[ak1+2][ar1] = a1.z; As[ak1+3][ar1] = a1.w;
    Bs[ak0+0][ar0] = b0.x; Bs[ak0+1][ar0] = b0.y; Bs[ak0+2][ar0] = b0.z; Bs[ak0+3][ar0] = b0.w;
    Bs[ak1+0][ar1] = b1.x; Bs[ak1+1][ar1] = b1.y; Bs[ak1+2][ar1] = b1.z; Bs[ak1+3][ar1] = b1.w;
    __syncthreads();
    #pragma unroll
    for (int kk = 0; kk < 16; ++kk) {
      float af[8], bf[8];
      #pragma unroll
      for (int i = 0; i < 8; ++i) af[i] = As[kk][ti*8 + i];
      #pragma unroll
      for (int j = 0; j < 8; ++j) bf[j] = Bs[kk][tj*8 + j];
      #pragma unroll
      for (int i = 0; i < 8; ++i)
        #pragma unroll
        for (int j = 0; j < 8; ++j) acc[i][j] += af[i] * bf[j];
    }
  }

  float bv[8];
  #pragma unroll
  for (int jj = 0; jj < 8; ++jj) {
    int n = bcol + tj*8 + jj;
    float bb = 0.f;
    if (bias1) bb += bias1[n];
    if (bias2) bb += bias2[n];
    bv[jj] = bb;
  }
  #pragma unroll
  for (int i = 0; i < 8; ++i) {
    int m = brow + ti*8 + i;
    float* cp = C + (size_t)m * N + bcol + tj*8;
    float4 v0 = make_float4(acc[i][0]+bv[0], acc[i][1]+bv[1], acc[i][2]+bv[2], acc[i][3]+bv[3]);
    float4 v1 = make_float4(acc[i][4]+bv[4], acc[i][5]+bv[5], acc[i][6]+bv[6], acc[i][7]+bv[7]);
    *(float4*)cp = v0;
    *(float4*)(cp + 4) = v1;
  }
}

// ---------------------------------------------------------------------------
// Persistent LSTM layer, cache-maintenance-free exchange.
// 256 blocks x 256 threads. Block owns 4 h-dims -> 16 Whh rows, held entirely
// in REGISTERS (16 float4/thread, interleaved k-slices). h_t staged in LDS.
// Cross-block exchange (h, flags) uses RELAXED agent-scope atomics only:
// they bypass L1/L2 to the coherence point, so no buffer_inv/wbl2 storms and
// gpre/Whh stay cache-resident. Arrival = one relaxed flag store (ordered
// after the h stores by s_waitcnt vmcnt(0)); wave 0 polls all 256 flags with
// ">= t+1" (monotonic, run-ahead-safe). c-state in wave-0 registers.
// Co-residency: 256 small blocks <= chip capacity under any packing.
// ---------------------------------------------------------------------------
__global__ __launch_bounds__(256, 1) void lstm_persist(
    const float* __restrict__ gpre,   // [t][b][gate*1024 + j], t-stride 16384
    const float* __restrict__ Whh,    // (4096, 1024)
    float* __restrict__ hseq,         // 513 slots of (4,1024); slot 0 unused
    unsigned* __restrict__ flag)      // 256 flags, zeroed by init_state
{
  __shared__ float hlds[4096];        // h_t  [b][k]           (16 KB)
  __shared__ float gsum[16][4];       // [row][b] full dot products

  const int tid = threadIdx.x;
  const int bid = blockIdx.x;
  const int rl = tid >> 4, ks = tid & 15;   // local row 0..15, k-split 0..15

  // --- one-time: this thread's weight slice into registers ---
  // row = gate*1024 + bid*4 + dim_local ; k-slice interleaved: float4 i at i*16+ks
  float4 wreg[16];
  {
    const int grow = (rl >> 2) * 1024 + bid * 4 + (rl & 3);
    const float4* wrow = (const float4*)(Whh + (size_t)grow * 1024);
    #pragma unroll
    for (int i = 0; i < 16; ++i) wreg[i] = wrow[i * 16 + ks];
  }
  // h_0 = 0 directly in LDS (no global slot-0 read)
  {
    float4* h4 = (float4*)hlds;
    #pragma unroll
    for (int i = 0; i < 4; ++i) h4[tid + 256 * i] = make_float4(0.f, 0.f, 0.f, 0.f);
  }
  float creg = 0.f;                          // cell state (tid<16 lanes)
  float gpv0 = 0.f, gpv1 = 0.f, gpv2 = 0.f, gpv3 = 0.f;
  const int gb = tid >> 2, gj = tid & 3;     // for tid<16: batch, dim-local
  if (tid < 16) {
    const float* gp = gpre + (size_t)gb * 4096 + bid * 4 + gj;
    gpv0 = gp[0]; gpv1 = gp[1024]; gpv2 = gp[2048]; gpv3 = gp[3072];
  }
  __syncthreads();

  const float4* hl4 = (const float4*)hlds;

  for (int t = 0; t < TT; ++t) {
    // --- dots: row rl, interleaved k-chunk ks (64 floats), 4 batches ---
    // LDS pattern: 16 ks-lanes read 256B contiguous (2-way, free); rl broadcast.
    float a0 = 0.f, a1 = 0.f, a2 = 0.f, a3 = 0.f;
    #pragma unroll
    for (int i = 0; i < 16; ++i) {
      const int k4 = i * 16 + ks;
      float4 w  = wreg[i];
      float4 h0 = hl4[k4];
      float4 h1 = hl4[256 + k4];
      float4 h2 = hl4[512 + k4];
      float4 h3 = hl4[768 + k4];
      a0 += w.x*h0.x + w.y*h0.y + w.z*h0.z + w.w*h0.w;
      a1 += w.x*h1.x + w.y*h1.y + w.z*h1.z + w.w*h1.w;
      a2 += w.x*h2.x + w.y*h2.y + w.z*h2.z + w.w*h2.w;
      a3 += w.x*h3.x + w.y*h3.y + w.z*h3.z + w.w*h3.w;
    }
    // reduce across the 16 ks-lanes (stays inside 16-lane groups)
    #pragma unroll
    for (int m = 8; m >= 1; m >>= 1) {
      a0 += __shfl_xor(a0, m, 64);
      a1 += __shfl_xor(a1, m, 64);
      a2 += __shfl_xor(a2, m, 64);
      a3 += __shfl_xor(a3, m, 64);
    }
    if (ks == 0) *(float4*)&gsum[rl][0] = make_float4(a0, a1, a2, a3);
    __syncthreads();                               // sync1: gsum ready

    // --- gates + state + h write (wave 0, lanes 0..15: (b, dim)) ---
    if (tid < 16) {
      float gi = gpv0 + gsum[     gj][gb];
      float gf = gpv1 + gsum[ 4 + gj][gb];
      float gg = gpv2 + gsum[ 8 + gj][gb];
      float go = gpv3 + gsum[12 + gj][gb];
      float c = sigmoidf(gf) * creg + sigmoidf(gi) * tanhf(gg);
      creg = c;
      float hv = sigmoidf(go) * tanhf(c);
      __hip_atomic_store(hseq + (size_t)(t + 1) * G4 + gb * 1024 + bid * 4 + gj,
                         hv, __ATOMIC_RELAXED, __HIP_MEMORY_SCOPE_AGENT);
    }

    if (t == TT - 1) break;   // h_512 stored; kernel-end completes it

    // --- arrival + gpre prefetch + poll (wave 0 only) ---
    if (tid < 64) {
      asm volatile("s_waitcnt vmcnt(0)" ::: "memory");   // h stores acked at IF
      if (tid == 0)
        __hip_atomic_store(flag + bid, (unsigned)(t + 1),
                           __ATOMIC_RELAXED, __HIP_MEMORY_SCOPE_AGENT);
      if (tid < 16) {  // prefetch next gpre slice (plain cached loads, read-only)
        const float* gp = gpre + (size_t)(t + 1) * 16384 + (size_t)gb * 4096 + bid * 4 + gj;
        gpv0 = gp[0]; gpv1 = gp[1024]; gpv2 = gp[2048]; gpv3 = gp[3072];
        asm volatile("" ::: "memory");                   // keep loads here
      }
      const unsigned tgt = (unsigned)(t + 1);
      for (;;) {
        unsigned f0 = __hip_atomic_load(flag + tid,       __ATOMIC_RELAXED, __HIP_MEMORY_SCOPE_AGENT);
        unsigned f1 = __hip_atomic_load(flag + tid +  64, __ATOMIC_RELAXED, __HIP_MEMORY_SCOPE_AGENT);
        unsigned f2 = __hip_atomic_load(flag + tid + 128, __ATOMIC_RELAXED, __HIP_MEMORY_SCOPE_AGENT);
        unsigned f3 = __hip_atomic_load(flag + tid + 192, __ATOMIC_RELAXED, __HIP_MEMORY_SCOPE_AGENT);
        if (__all((f0 >= tgt) && (f1 >= tgt) && (f2 >= tgt) && (f3 >= tgt))) break;
      }
    }
    __syncthreads();                               // sync2: all flags seen

    // --- stage h_{t+1} into LDS (IF-bypassing 8B atomic loads) ---
    {
      const unsigned long long* hs =
          (const unsigned long long*)(hseq + (size_t)(t + 1) * G4);
      unsigned long long* hd = (unsigned long long*)hlds;
      #pragma unroll
      for (int i = 0; i < 8; ++i)
        hd[tid + 256 * i] = __hip_atomic_load(hs + tid + 256 * i,
                                              __ATOMIC_RELAXED, __HIP_MEMORY_SCOPE_AGENT);
    }
    __syncthreads();                               // sync-top: hlds = h_{t+1}
  }
}

// Per-row (b,t) stats over logits in d_out:
__global__ __launch_bounds__(256) void row_stats(
    const float* __restrict__ logits, float* __restrict__ rowA, float* __restrict__ rowE)
{
  const int m = blockIdx.x;
  const float* row = logits + (size_t)m * VV;
  __shared__ float red[8];
  const int tid = threadIdx.x;

  float mx = -3.0e38f;
  for (int v = tid; v < EOSI; v += 256) mx = fmaxf(mx, row[v]);
  for (int off = 32; off; off >>= 1) mx = fmaxf(mx, __shfl_down(mx, off, 64));
  if ((tid & 63) == 0) red[tid >> 6] = mx;
  __syncthreads();
  if (tid == 0) red[4] = fmaxf(fmaxf(red[0], red[1]), fmaxf(red[2], red[3]));
  __syncthreads();
  mx = red[4];

  float s = 0.f;
  for (int v = tid; v < EOSI; v += 256) s += expf(row[v] - mx);
  for (int off = 32; off; off >>= 1) s += __shfl_down(s, off, 64);
  if ((tid & 63) == 0) red[tid >> 6] = s;
  __syncthreads();

  if (tid == 0) {
    s = red[0] + red[1] + red[2] + red[3];
    float lse_v = mx + logf(s);
    float eos = row[EOSI];
    int t = m & 511;                         // m = b*512 + t
    float log_lb = (float)(t + 1) * LOG_BOUND;
    float log_eos_lb = -softplusf(eos);      // log_sigmoid(-eos)
    float log_eos_ub = -softplusf(-eos);     // log_sigmoid(eos)
    float shift = log_lb + log_eos_lb;
    float f_lb = -expm1f(log_lb);            // 1 - exp(log_lb)
    float log_lb_eos = logf(f_lb) + log_eos_lb;
    float lprob_eos = log_lb_eos + softplusf(log_eos_ub - log_lb_eos);
    float aa = shift, bb = lprob_eos;
    float lse2 = fmaxf(aa, bb) + log1pf(expf(-fabsf(aa - bb)));
    rowA[m] = lse_v + lse2 - shift;
    rowE[m] = lprob_eos - lse2;
  }
}

// out[m][v] = logit - rowA[m] for v < EOSI ; rowE[m] at v == EOSI. In-place, float4.
__global__ __launch_bounds__(256) void finalize(
    float* __restrict__ out, const float* __restrict__ rowA, const float* __restrict__ rowE)
{
  const int m = blockIdx.y;
  const int v4 = blockIdx.x * 256 + threadIdx.x;   // 8000 float4 per row
  if (v4 >= 8000) return;
  float4* rp = (float4*)(out + (size_t)m * VV);
  const float A = rowA[m];
  float4 p = rp[v4];
  p.x -= A; p.y -= A; p.z -= A; p.w -= A;
  if (v4 == 7999) p.w = rowE[m];
  rp[v4] = p;
}

extern "C" void kernel_launch(void* const* d_in, const int* in_sizes, int n_in,
                              void* d_out, int out_size, void* d_ws, size_t ws_size,
                              hipStream_t stream)
{
  const int*   tokens = (const int*)  d_in[0];
  const float* emb    = (const float*)d_in[1];
  const float* Wproj  = (const float*)d_in[2];
  const float* Wih0   = (const float*)d_in[3];
  const float* Whh0   = (const float*)d_in[4];
  const float* bih0   = (const float*)d_in[5];
  const float* bhh0   = (const float*)d_in[6];
  const float* Wih1   = (const float*)d_in[7];
  const float* Whh1   = (const float*)d_in[8];
  const float* bih1   = (const float*)d_in[9];
  const float* bhh1   = (const float*)d_in[10];
  float* out = (float*)d_out;

  // workspace layout (floats): ~84 MB total
  float* ws = (float*)d_ws;
  float* g0   = ws;                        // 2048 x 4096
  float* g1   = g0 + (size_t)2048*4096;
  float* h0   = g1 + (size_t)2048*4096;    // 513 slots of (4,1024); slot 0 unused
  float* h1   = h0 + (size_t)513*4096;
  unsigned* flag0 = (unsigned*)(h1 + (size_t)513*4096);  // 256 each
  unsigned* flag1 = flag0 + 256;
  float* rowA = (float*)(flag1 + 256);     // 2048
  float* rowE = rowA + 2048;

  init_state<<<1, 256, 0, stream>>>(flag0, flag1);

  // layer 0 input gates for all (t,b): emb[tokens] @ Wih0^T + bih0 + bhh0
  gemm_nt<<<dim3(32, 16), 256, 0, stream>>>(emb, Wih0, g0, 2048, 4096, 1024,
                                            bih0, bhh0, tokens, 1);
  lstm_persist<<<NBLK, 256, 0, stream>>>(g0, Whh0, h0, flag0);

  // layer 1 input gates: h0_all @ Wih1^T + bih1 + bhh1
  gemm_nt<<<dim3(32, 16), 256, 0, stream>>>(h0 + 4096, Wih1, g1, 2048, 4096, 1024,
                                            bih1, bhh1, nullptr, 0);
  lstm_persist<<<NBLK, 256, 0, stream>>>(g1, Whh1, h1, flag1);

  // projection: logits into d_out, layout (b, t, v)
  gemm_nt<<<dim3(250, 16), 256, 0, stream>>>(h1, Wproj, out, 2048, 32000, 1024,
                                             nullptr, nullptr, nullptr, 2);

  row_stats<<<2048, 256, 0, stream>>>(out, rowA, rowE);
  finalize<<<dim3(32, 2048), 256, 0, stream>>>(out, rowA, rowE);
}